// Round 3
// baseline (423.626 us; speedup 1.0000x reference)
//
#include <hip/hip_runtime.h>
#include <math.h>

#define BB 2
#define TT 512
#define CC 64
#define HH 64
#define KK 128            // 2C
#define JT 64             // j-tile per block

typedef __attribute__((ext_vector_type(8))) short short8;
typedef __attribute__((ext_vector_type(4))) float float4v;

__device__ inline unsigned short f2bf(float f) {
    unsigned int u = __float_as_uint(f);
    u = (u + 0x7FFFu + ((u >> 16) & 1u)) >> 16;   // RNE
    return (unsigned short)u;
}

__device__ inline short8 cvt8(float4 a, float4 b) {
    short8 r;
    r[0] = (short)f2bf(a.x); r[1] = (short)f2bf(a.y);
    r[2] = (short)f2bf(a.z); r[3] = (short)f2bf(a.w);
    r[4] = (short)f2bf(b.x); r[5] = (short)f2bf(b.y);
    r[6] = (short)f2bf(b.z); r[7] = (short)f2bf(b.w);
    return r;
}

// ---------------------------------------------------------------------------
// pack_kernel: Wpt[c][k] = bf16(W1p[k][c]), tight stride KK. 8192 elems.
// ---------------------------------------------------------------------------
__global__ __launch_bounds__(256) void pack_kernel(
    const float* __restrict__ W1, unsigned short* __restrict__ Wpt)
{
    int t = blockIdx.x * 256 + threadIdx.x;     // 0..8191
    int c = t >> 7;                             // 0..63
    int k = t & 127;                            // 0..127
    Wpt[c * KK + k] = f2bf(W1[(2 * CC + k) * CC + c]);
}

// ---------------------------------------------------------------------------
// prep: kp = (x+pos)@W1k ; qpb = (x+pos)@W1q + b1 ; v = x@Wv + bv
// ---------------------------------------------------------------------------
__global__ __launch_bounds__(64) void prep_kernel(
    const float* __restrict__ x, const float* __restrict__ pos_emb,
    const float* __restrict__ W1, const float* __restrict__ b1,
    const float* __restrict__ Wv, const float* __restrict__ bv,
    float* __restrict__ kp, float* __restrict__ qpb, float* __restrict__ v)
{
    const int row = blockIdx.x;          // b*T + t
    const int t = row & (TT - 1);
    const int c = threadIdx.x;           // 0..63
    __shared__ float xs[CC], x1s[CC];
    float xv = x[row * CC + c];
    xs[c] = xv;
    x1s[c] = xv + pos_emb[t * CC + c];
    __syncthreads();
    float ak = 0.f, aq = 0.f, av = 0.f;
#pragma unroll 8
    for (int k = 0; k < CC; ++k) {
        ak = fmaf(x1s[k], W1[k * CC + c], ak);
        aq = fmaf(x1s[k], W1[(CC + k) * CC + c], aq);
        av = fmaf(xs[k], Wv[k * HH + c], av);
    }
    kp[row * CC + c] = ak;
    qpb[row * CC + c] = aq + b1[c];
    v[row * HH + c] = av + bv[c];
}

// ---------------------------------------------------------------------------
// wei_kernel v3: barrier-free, LDS-free bf16 MFMA.
// Block = (b, i, j-tile of 64); wave w owns rows j0+w*16..+15.
// Lane (m=lane&15, kg=lane>>4) loads its A fragment DIRECTLY from pd
// (32 contiguous fp32 bytes per kt), converts in regs; B frags come from
// prepacked Wpt (16 KB, L1/L2-hot). No __syncthreads anywhere.
// ---------------------------------------------------------------------------
__global__ __launch_bounds__(256) void wei_kernel(
    const float* __restrict__ pd, const unsigned short* __restrict__ Wpt,
    const float* __restrict__ W2, const float* __restrict__ b2,
    const float* __restrict__ kp, const float* __restrict__ qpb,
    float* __restrict__ wei)
{
    const int i = blockIdx.y;
    const int b = blockIdx.z;
    const int j0 = blockIdx.x * JT;
    if (j0 > i) return;                  // uniform early exit

    const int tid = threadIdx.x;
    const int wave = tid >> 6;
    const int lane = tid & 63;
    const int m = lane & 15;             // A j-row low bits / B,C channel
    const int kg = lane >> 4;            // k-group (8 k's)

    const int jrow = j0 + wave * 16 + m;                       // <= 511 always
    const float* __restrict__ arow =
        pd + (((size_t)b * TT + i) * TT + jrow) * KK + kg * 8; // lane's k base

    // issue all 8 A loads up front (128 B/lane, fills the line with kg peers)
    float4 av[8];
#pragma unroll
    for (int kt = 0; kt < 4; ++kt) {
        av[2 * kt]     = *(const float4*)(arow + kt * 32);
        av[2 * kt + 1] = *(const float4*)(arow + kt * 32 + 4);
    }

    float4v acc[4] = {{0.f,0.f,0.f,0.f},{0.f,0.f,0.f,0.f},
                      {0.f,0.f,0.f,0.f},{0.f,0.f,0.f,0.f}};
#pragma unroll
    for (int kt = 0; kt < 4; ++kt) {
        short8 a = cvt8(av[2 * kt], av[2 * kt + 1]);
#pragma unroll
        for (int nt = 0; nt < 4; ++nt) {
            short8 bf = *(const short8*)&Wpt[(nt * 16 + m) * KK + kt * 32 + kg * 8];
            acc[nt] = __builtin_amdgcn_mfma_f32_16x16x32_bf16(a, bf, acc[nt], 0, 0, 0);
        }
    }

    // ---- epilogue: gelu + dot(W2) via 16-lane butterfly + store ----
    float w2v[4], qv[4];
#pragma unroll
    for (int nt = 0; nt < 4; ++nt) {
        int c = nt * 16 + m;
        w2v[nt] = W2[c];
        qv[nt] = qpb[((size_t)b * TT + i) * CC + c];
    }
    const float b2v = b2[0];

#pragma unroll
    for (int r = 0; r < 4; ++r) {
        const int j = j0 + wave * 16 + kg * 4 + r;   // C row = kg*4 + r
        float s = 0.f;
#pragma unroll
        for (int nt = 0; nt < 4; ++nt) {
            float tv = acc[nt][r] + qv[nt] + kp[((size_t)b * TT + j) * CC + nt * 16 + m];
            float g = 0.5f * tv * (1.f + erff(tv * 0.70710678118654752f));
            s = fmaf(g, w2v[nt], s);
        }
#pragma unroll
        for (int off = 1; off < 16; off <<= 1) s += __shfl_xor(s, off);
        if (m == r && j <= i)
            wei[((size_t)b * TT + i) * TT + j] = (s + b2v) * 0.125f;
    }
}

// ---------------------------------------------------------------------------
// out_kernel: causal softmax over j in [0,i], then out[b,i,:] = p @ v
// ---------------------------------------------------------------------------
__device__ inline float wave_reduce_max(float m) {
#pragma unroll
    for (int off = 32; off > 0; off >>= 1) m = fmaxf(m, __shfl_down(m, off));
    return m;
}
__device__ inline float wave_reduce_sum(float s) {
#pragma unroll
    for (int off = 32; off > 0; off >>= 1) s += __shfl_down(s, off);
    return s;
}

__global__ __launch_bounds__(256) void out_kernel(
    const float* __restrict__ wei, const float* __restrict__ v,
    float* __restrict__ out)
{
    const int i = blockIdx.x;
    const int b = blockIdx.y;
    const int tid = threadIdx.x;
    const int wv = tid >> 6;
    const int lane = tid & 63;
    const int n = i + 1;

    __shared__ float p[TT];
    __shared__ float red[4];
    __shared__ float part[4][HH];

    float m = -1e30f;
    for (int jj = tid; jj < n; jj += 256) {
        float w = wei[((size_t)b * TT + i) * TT + jj];
        p[jj] = w;
        m = fmaxf(m, w);
    }
    m = wave_reduce_max(m);
    if (lane == 0) red[wv] = m;
    __syncthreads();
    const float M = fmaxf(fmaxf(red[0], red[1]), fmaxf(red[2], red[3]));
    __syncthreads();

    float s = 0.f;
    for (int jj = tid; jj < n; jj += 256) {
        float e = __expf(p[jj] - M);
        p[jj] = e;
        s += e;
    }
    s = wave_reduce_sum(s);
    if (lane == 0) red[wv] = s;
    __syncthreads();
    const float S = red[0] + red[1] + red[2] + red[3];
    const float inv = 1.f / S;

    float a0 = 0.f, a1 = 0.f, a2 = 0.f, a3 = 0.f;
    int jj = wv;
    for (; jj + 12 < n; jj += 16) {
        a0 = fmaf(p[jj],      v[((size_t)b * TT + jj) * HH + lane], a0);
        a1 = fmaf(p[jj + 4],  v[((size_t)b * TT + jj + 4) * HH + lane], a1);
        a2 = fmaf(p[jj + 8],  v[((size_t)b * TT + jj + 8) * HH + lane], a2);
        a3 = fmaf(p[jj + 12], v[((size_t)b * TT + jj + 12) * HH + lane], a3);
    }
    for (; jj < n; jj += 4)
        a0 = fmaf(p[jj], v[((size_t)b * TT + jj) * HH + lane], a0);
    part[wv][lane] = a0 + a1 + a2 + a3;
    __syncthreads();
    if (tid < HH) {
        float r = (part[0][tid] + part[1][tid] + part[2][tid] + part[3][tid]) * inv;
        out[((size_t)b * TT + i) * HH + tid] = r;
    }
}

// ---------------------------------------------------------------------------
extern "C" void kernel_launch(void* const* d_in, const int* in_sizes, int n_in,
                              void* d_out, int out_size, void* d_ws, size_t ws_size,
                              hipStream_t stream)
{
    const float* x       = (const float*)d_in[0];
    const float* pos_emb = (const float*)d_in[1];
    const float* pd      = (const float*)d_in[2];
    const float* W1      = (const float*)d_in[3];
    const float* b1      = (const float*)d_in[4];
    const float* W2      = (const float*)d_in[5];
    const float* b2      = (const float*)d_in[6];
    const float* Wv      = (const float*)d_in[7];
    const float* bv      = (const float*)d_in[8];
    float* out = (float*)d_out;

    float* ws = (float*)d_ws;
    // layout (floats): Wpt [4096] | kp [65536] | qpb [65536] | v [65536] | wei [524288]
    unsigned short* Wpt = (unsigned short*)ws;          // 64*128 ushorts = 4096 floats
    float* kp  = ws + 4096;
    float* qpb = ws + 4096 + 65536;
    float* v   = ws + 4096 + 131072;
    float* wei = ws + 4096 + 196608;

    pack_kernel<<<dim3(32), dim3(256), 0, stream>>>(W1, Wpt);
    prep_kernel<<<dim3(BB * TT), dim3(64), 0, stream>>>(x, pos_emb, W1, b1, Wv, bv, kp, qpb, v);
    wei_kernel<<<dim3(TT / JT, TT, BB), dim3(256), 0, stream>>>(pd, Wpt, W2, b2, kp, qpb, wei);
    out_kernel<<<dim3(TT, BB), dim3(256), 0, stream>>>(wei, v, out);
}

// Round 4
// 417.822 us; speedup vs baseline: 1.0139x; 1.0139x over previous
//
#include <hip/hip_runtime.h>
#include <math.h>

#define BB 2
#define TT 512
#define CC 64
#define HH 64
#define KP 128              // pd K
#define KA 192              // augmented K: 128 pd + 64 x1  (6 mfma k-steps)
#define PADB 198            // Bext LDS row stride in shorts (99 dwords: odd -> bank spread)
#define JT 64

typedef __attribute__((ext_vector_type(8))) short short8;
typedef __attribute__((ext_vector_type(4))) float float4v;

__device__ inline unsigned short f2bf(float f) {
    unsigned int u = __float_as_uint(f);
    u = (u + 0x7FFFu + ((u >> 16) & 1u)) >> 16;   // RNE
    return (unsigned short)u;
}

__device__ inline short8 cvt8(float4 a, float4 b) {
    short8 r;
    r[0] = (short)f2bf(a.x); r[1] = (short)f2bf(a.y);
    r[2] = (short)f2bf(a.z); r[3] = (short)f2bf(a.w);
    r[4] = (short)f2bf(b.x); r[5] = (short)f2bf(b.y);
    r[6] = (short)f2bf(b.z); r[7] = (short)f2bf(b.w);
    return r;
}

// Branchless exact-erf gelu (A&S 7.1.26, |erf err| <= 1.5e-7).
__device__ inline float gelu_erf(float x) {
    float z = fabsf(x) * 0.70710678118654752f;
    float t = __builtin_amdgcn_rcpf(fmaf(0.3275911f, z, 1.f));
    float poly = fmaf(fmaf(fmaf(fmaf(1.061405429f, t, -1.453152027f),
                                t, 1.421413741f),
                           t, -0.284496736f),
                      t, 0.254829592f) * t;
    float erfc_ = poly * __expf(-z * z);          // 1 - erf(|z|)
    float onePlus = (x >= 0.f) ? (2.f - erfc_) : erfc_;   // 1 + erf(signed)
    return 0.5f * x * onePlus;
}

// ---------------------------------------------------------------------------
// pack_kernel: Bext[c][k] (bf16, stride PADB):
//   k <  128 : W1p[k][c]   (W1 rows 128..255)
//   k <  192 : W1k[k-128][c] (W1 rows 0..63)  -> MFMA computes pp + kp fused
// ---------------------------------------------------------------------------
__global__ __launch_bounds__(256) void pack_kernel(
    const float* __restrict__ W1, unsigned short* __restrict__ Bext)
{
    int t = blockIdx.x * 256 + threadIdx.x;
    if (t >= CC * PADB) return;
    int c = t / PADB;
    int k = t - c * PADB;
    float val = 0.f;
    if (k < 128)      val = W1[(2 * CC + k) * CC + c];
    else if (k < 192) val = W1[(k - 128) * CC + c];
    Bext[c * PADB + k] = f2bf(val);
}

// ---------------------------------------------------------------------------
// prep: x1bf = bf16(x+pos) ; qpb = (x+pos)@W1q + b1 ; v = x@Wv + bv
// ---------------------------------------------------------------------------
__global__ __launch_bounds__(64) void prep_kernel(
    const float* __restrict__ x, const float* __restrict__ pos_emb,
    const float* __restrict__ W1, const float* __restrict__ b1,
    const float* __restrict__ Wv, const float* __restrict__ bv,
    unsigned short* __restrict__ x1bf, float* __restrict__ qpb,
    float* __restrict__ v)
{
    const int row = blockIdx.x;          // b*T + t
    const int t = row & (TT - 1);
    const int c = threadIdx.x;           // 0..63
    __shared__ float xs[CC], x1s[CC];
    float xv = x[row * CC + c];
    xs[c] = xv;
    float x1v = xv + pos_emb[t * CC + c];
    x1s[c] = x1v;
    __syncthreads();
    float aq = 0.f, av = 0.f;
#pragma unroll 8
    for (int k = 0; k < CC; ++k) {
        aq = fmaf(x1s[k], W1[(CC + k) * CC + c], aq);   // W1q rows C..2C-1
        av = fmaf(xs[k], Wv[k * HH + c], av);
    }
    x1bf[row * CC + c] = f2bf(x1v);
    qpb[row * CC + c] = aq + b1[c];
    v[row * HH + c] = av + bv[c];
}

// ---------------------------------------------------------------------------
// attn_kernel: block = (b, i). Loops over causal j-tiles of 64 with software
// prefetch (tile t+1 loads issued before tile t compute). Per tile:
//   A = [bf16(pd[b,i,j,:]) | x1bf[b,j,:]]  (K=192), B = Bext (LDS, staged once)
//   acc = pp + kp; epilogue gelu+W2-dot -> logits into LDS p[].
// Then in-block softmax over j<=i and p@v -> out[b,i,:]. No wei in HBM.
// i remap pairs small and large rows per CU batch for load balance.
// ---------------------------------------------------------------------------
__global__ __launch_bounds__(256, 4) void attn_kernel(
    const float* __restrict__ pd, const unsigned short* __restrict__ Bext,
    const unsigned short* __restrict__ x1bf, const float* __restrict__ qpb,
    const float* __restrict__ W2, const float* __restrict__ b2,
    const float* __restrict__ v, float* __restrict__ out)
{
    const int bx = blockIdx.x;
    const int i = (bx < 256) ? bx : 767 - bx;    // per-CU work balancing
    const int b = blockIdx.y;
    const int tid = threadIdx.x;
    const int wave = tid >> 6, lane = tid & 63;
    const int m = lane & 15, kg = lane >> 4;

    __shared__ unsigned short Blds[CC * PADB];   // 25344 B
    __shared__ float p[TT];
    __shared__ float red[4];
    __shared__ float part[4][HH];

    // ---- stage Bext -> LDS (once) ----
    {
        const uint4* __restrict__ src = (const uint4*)Bext;
        uint4* dst = (uint4*)Blds;
        for (int f = tid; f < (CC * PADB) / 8; f += 256) dst[f] = src[f];
    }
    // ---- per-block constants ----
    float w2v[4], qv[4];
#pragma unroll
    for (int nt = 0; nt < 4; ++nt) {
        int c = nt * 16 + m;
        w2v[nt] = W2[c];
        qv[nt] = qpb[((size_t)b * TT + i) * CC + c];
    }
    const float b2v = b2[0];
    __syncthreads();

    const int ntiles = (i + JT) / JT;            // ceil((i+1)/64)
    const int jrb = wave * 16 + m;               // lane's A row within tile
    const float* __restrict__ pdb = pd + ((size_t)b * TT + i) * TT * KP;
    const unsigned short* __restrict__ xb = x1bf + (size_t)b * TT * CC;

    float4 av[8];
    short8 ax[2];
    auto load_tile = [&](int t) {
        const float* __restrict__ ar = pdb + (size_t)(t * JT + jrb) * KP + kg * 8;
#pragma unroll
        for (int kt = 0; kt < 4; ++kt) {
            av[2 * kt]     = *(const float4*)(ar + kt * 32);
            av[2 * kt + 1] = *(const float4*)(ar + kt * 32 + 4);
        }
        const unsigned short* __restrict__ xr = xb + (size_t)(t * JT + jrb) * CC + kg * 8;
        ax[0] = *(const short8*)xr;
        ax[1] = *(const short8*)(xr + 32);
    };

    load_tile(0);

    for (int t = 0; t < ntiles; ++t) {
        // convert current tile's A into frags (frees av/ax for prefetch)
        short8 af[6];
#pragma unroll
        for (int kt = 0; kt < 4; ++kt) af[kt] = cvt8(av[2 * kt], av[2 * kt + 1]);
        af[4] = ax[0];
        af[5] = ax[1];

        if (t + 1 < ntiles) load_tile(t + 1);    // prefetch flies over compute

        float4v acc[4] = {{0.f,0.f,0.f,0.f},{0.f,0.f,0.f,0.f},
                          {0.f,0.f,0.f,0.f},{0.f,0.f,0.f,0.f}};
#pragma unroll
        for (int kt = 0; kt < 6; ++kt) {
#pragma unroll
            for (int nt = 0; nt < 4; ++nt) {
                short8 bf = *(const short8*)&Blds[(nt * 16 + m) * PADB + kt * 32 + kg * 8];
                acc[nt] = __builtin_amdgcn_mfma_f32_16x16x32_bf16(af[kt], bf, acc[nt], 0, 0, 0);
            }
        }

        const int j0 = t * JT + wave * 16 + kg * 4;
#pragma unroll
        for (int r = 0; r < 4; ++r) {
            const int j = j0 + r;
            float s = 0.f;
#pragma unroll
            for (int nt = 0; nt < 4; ++nt)
                s = fmaf(gelu_erf(acc[nt][r] + qv[nt]), w2v[nt], s);
#pragma unroll
            for (int off = 1; off < 16; off <<= 1) s += __shfl_xor(s, off);
            if (m == r)
                p[j] = (j <= i) ? (s + b2v) * 0.125f : -1e30f;
        }
    }
    __syncthreads();

    // ---- softmax over j in [0, i] ----
    const int n = i + 1;
    float mx = -1e30f;
    for (int jj = tid; jj < n; jj += 256) mx = fmaxf(mx, p[jj]);
#pragma unroll
    for (int off = 32; off > 0; off >>= 1) mx = fmaxf(mx, __shfl_down(mx, off));
    if (lane == 0) red[wave] = mx;
    __syncthreads();
    const float M = fmaxf(fmaxf(red[0], red[1]), fmaxf(red[2], red[3]));
    __syncthreads();

    float sm = 0.f;
    for (int jj = tid; jj < n; jj += 256) {
        float e = __expf(p[jj] - M);
        p[jj] = e;
        sm += e;
    }
#pragma unroll
    for (int off = 32; off > 0; off >>= 1) sm += __shfl_down(sm, off);
    if (lane == 0) red[wave] = sm;
    __syncthreads();
    const float inv = 1.f / (red[0] + red[1] + red[2] + red[3]);

    // ---- p @ v ----
    float a0 = 0.f, a1 = 0.f, a2 = 0.f, a3 = 0.f;
    int jj = wave;
    for (; jj + 12 < n; jj += 16) {
        a0 = fmaf(p[jj],      v[((size_t)b * TT + jj) * HH + lane], a0);
        a1 = fmaf(p[jj + 4],  v[((size_t)b * TT + jj + 4) * HH + lane], a1);
        a2 = fmaf(p[jj + 8],  v[((size_t)b * TT + jj + 8) * HH + lane], a2);
        a3 = fmaf(p[jj + 12], v[((size_t)b * TT + jj + 12) * HH + lane], a3);
    }
    for (; jj < n; jj += 4)
        a0 = fmaf(p[jj], v[((size_t)b * TT + jj) * HH + lane], a0);
    part[wave][lane] = a0 + a1 + a2 + a3;
    __syncthreads();
    if (tid < HH) {
        float r = (part[0][tid] + part[1][tid] + part[2][tid] + part[3][tid]) * inv;
        out[((size_t)b * TT + i) * HH + tid] = r;
    }
}

// ---------------------------------------------------------------------------
extern "C" void kernel_launch(void* const* d_in, const int* in_sizes, int n_in,
                              void* d_out, int out_size, void* d_ws, size_t ws_size,
                              hipStream_t stream)
{
    const float* x       = (const float*)d_in[0];
    const float* pos_emb = (const float*)d_in[1];
    const float* pd      = (const float*)d_in[2];
    const float* W1      = (const float*)d_in[3];
    const float* b1      = (const float*)d_in[4];
    const float* W2      = (const float*)d_in[5];
    const float* b2      = (const float*)d_in[6];
    const float* Wv      = (const float*)d_in[7];
    const float* bv      = (const float*)d_in[8];
    float* out = (float*)d_out;

    float* ws = (float*)d_ws;
    // layout (floats): Bext [6400] | x1bf [32768] | qpb [65536] | v [65536]
    unsigned short* Bext = (unsigned short*)ws;            // 64*198 shorts
    unsigned short* x1bf = (unsigned short*)(ws + 6400);   // B*T*C shorts
    float* qpb = ws + 6400 + 32768;
    float* v   = ws + 6400 + 32768 + 65536;

    pack_kernel<<<dim3((CC * PADB + 255) / 256), dim3(256), 0, stream>>>(W1, Bext);
    prep_kernel<<<dim3(BB * TT), dim3(64), 0, stream>>>(x, pos_emb, W1, b1, Wv, bv, x1bf, qpb, v);
    attn_kernel<<<dim3(TT, BB), dim3(256), 0, stream>>>(pd, Bext, x1bf, qpb, W2, b2, v, out);
}